// Round 4
// baseline (257.976 us; speedup 1.0000x reference)
//
#include <hip/hip_runtime.h>
#include <math.h>

// Problem constants: B=4,S=4096,IN=2048,E=16,D=128,A=128,R=4
#define NTOK   16384
#define INDIM  2048
#define NROWS  20      // 16 Wv rows + 4 mlp_w1 rows
#define CHUNK  256     // K-chunk (floats): 1 KB per row, 8 chunks

// workspace (float) layout
#define WS_PKT  0      // PKt[e2][r][e]  : 16*4*16 = 1024
#define WS_D1K  1024   // [e2][e] 256
#define WS_GQK  1280   // [e2][e] 256
#define WS_BQK  1536   // [e2][e] 256
#define WS_SCAL 1792   // m0,q0,mW[4],q1[4],Q2[16] = 26
#define WS_TOT  1818

#define SIM_SCALE 0.08838834764831845f  // 1/sqrt(128)

// LDS layout (floats): scat[t][w][i] = t*320+w*16+i (1280), red[t][w] @1280 (+80)
#define LSCAT_T 320
#define LRED    1280

__device__ __forceinline__ float fma4(float4 a, float4 b, float acc) {
    return fmaf(a.x, b.x, fmaf(a.y, b.y, fmaf(a.z, b.z, fmaf(a.w, b.w, acc))));
}

// Hidden K-chunk -> registers. Lane l covers K-slice [l*4, l*4+4) of the
// chunk for this wave's 4 tokens: 4 coalesced global_load_dwordx4.
__device__ __forceinline__ void load_h(float4 h[4], const float* __restrict__ hb,
                                       int goff) {
    #pragma unroll
    for (int t = 0; t < 4; ++t)
        h[t] = *(const float4*)(hb + t * INDIM + goff);
}

// One half-chunk: 10 weight rows [R0, R0+10) -> regs (L1/L2-hot), 160 FMA.
// Keeping halves separated by sched_barrier(0) caps live w-regs at 40 so the
// kernel stays <=168 VGPR -> 3 waves/SIMD.
template<int R0>
__device__ __forceinline__ void half10(float acc[NROWS][4],
                                       const float* __restrict__ wvl,
                                       const float* __restrict__ w1l,
                                       int goff, const float4 h[4]) {
    float4 w[10];
    #pragma unroll
    for (int j = 0; j < 10; ++j) {
        const int r = R0 + j;
        const float* src = (r < 16) ? (wvl + (r << 11)) : (w1l + ((r - 16) << 11));
        w[j] = *(const float4*)(src + goff);
    }
    #pragma unroll
    for (int j = 0; j < 10; ++j) {
        #pragma unroll
        for (int t = 0; t < 4; ++t)
            acc[R0 + j][t] = fma4(h[t], w[j], acc[R0 + j][t]);
    }
}

__device__ __forceinline__ void chunk(float acc[NROWS][4],
                                      const float* __restrict__ wvl,
                                      const float* __restrict__ w1l,
                                      int goff, const float4 h[4]) {
    half10<0>(acc, wvl, w1l, goff, h);
    __builtin_amdgcn_sched_barrier(0);   // cap live w regs at 40
    half10<10>(acc, wvl, w1l, goff, h);
    __builtin_amdgcn_sched_barrier(0);   // keep next loads from hoisting in
}

// ---------------------------------------------------------------------------
// Precompute kernel: 17 blocks x 256 threads (unchanged, known-good).
// ---------------------------------------------------------------------------
__global__ __launch_bounds__(256) void hr_pre2(
    const float* __restrict__ ee, const float* __restrict__ gam,
    const float* __restrict__ bta, const float* __restrict__ w2,
    const float* __restrict__ b2, const float* __restrict__ wq,
    const float* __restrict__ wk, float* __restrict__ ws)
{
    const int tid  = threadIdx.x;
    const int bx   = blockIdx.x;
    const int lane = tid & 63;
    const int wave = tid >> 6;

    if (bx == 16) {
        __shared__ float sacc[26];
        if (tid < 26) sacc[tid] = 0.f;
        __syncthreads();
        float pa[26];
        #pragma unroll
        for (int j = 0; j < 26; ++j) pa[j] = 0.f;
        for (int i = tid; i < 2048; i += 256) {
            float b = b2[i];
            float4 w4 = *(const float4*)(w2 + i * 4);
            float wr[4] = {w4.x, w4.y, w4.z, w4.w};
            pa[0] += b;
            pa[1] += b * b;
            #pragma unroll
            for (int r = 0; r < 4; ++r) {
                pa[2 + r] += wr[r];
                pa[6 + r] += b * wr[r];
                #pragma unroll
                for (int r2 = 0; r2 < 4; ++r2) pa[10 + r * 4 + r2] += wr[r] * wr[r2];
            }
        }
        #pragma unroll
        for (int j = 0; j < 26; ++j) {
            float v = pa[j];
            v += __shfl_xor(v, 32); v += __shfl_xor(v, 16); v += __shfl_xor(v, 8);
            v += __shfl_xor(v, 4);  v += __shfl_xor(v, 2);  v += __shfl_xor(v, 1);
            if (lane == 0) atomicAdd(&sacc[j], v);
        }
        __syncthreads();
        if (tid < 26) ws[WS_SCAL + tid] = sacc[tid] * (1.f / 2048.f);
        return;
    }

    const int e2 = bx;
    __shared__ float sge[128];
    __shared__ float sK[128];
    __shared__ float sWqK[128];
    __shared__ float sred[8];

    float v8[8];
    float s = 0.f;
    #pragma unroll
    for (int j = 0; j < 8; ++j) { v8[j] = ee[tid + j * 256]; s += v8[j]; }
    s += __shfl_xor(s, 32); s += __shfl_xor(s, 16); s += __shfl_xor(s, 8);
    s += __shfl_xor(s, 4);  s += __shfl_xor(s, 2);  s += __shfl_xor(s, 1);
    if (lane == 0) sred[wave] = s;
    __syncthreads();
    const float mu = (sred[0] + sred[1] + sred[2] + sred[3]) * (1.f / 2048.f);
    float q = 0.f;
    #pragma unroll
    for (int j = 0; j < 8; ++j) { float d = v8[j] - mu; q += d * d; }
    q += __shfl_xor(q, 32); q += __shfl_xor(q, 16); q += __shfl_xor(q, 8);
    q += __shfl_xor(q, 4);  q += __shfl_xor(q, 2);  q += __shfl_xor(q, 1);
    if (lane == 0) sred[4 + wave] = q;
    __syncthreads();
    const float rsq = rsqrtf((sred[4] + sred[5] + sred[6] + sred[7]) * (1.f / 2048.f) + 1e-5f);

    if (tid < 128) {
        int idx = (e2 << 7) + tid;
        sge[tid] = (ee[idx] - mu) * rsq * gam[idx] + bta[idx];
    }
    __syncthreads();

    {
        int a = tid >> 1, half = tid & 1;
        const float* wr = wk + (a << 7) + (half << 6);
        const float* gg = sge + (half << 6);
        float acc = 0.f;
        #pragma unroll 8
        for (int j = 0; j < 64; ++j) acc = fmaf(gg[j], wr[j], acc);
        acc += __shfl_xor(acc, 1);
        if (half == 0) sK[a] = acc;
    }
    __syncthreads();

    {
        int d = tid >> 1, half = tid & 1;
        float acc = 0.f;
        #pragma unroll 8
        for (int j = 0; j < 64; ++j) {
            int a = (half << 6) + j;
            acc = fmaf(wq[(a << 7) + d], sK[a], acc);
        }
        acc += __shfl_xor(acc, 1);
        if (half == 0) sWqK[d] = acc;
    }
    __syncthreads();

    {
        int o = tid >> 2, qd = tid & 3;
        int r = o >> 4, e = o & 15;
        float acc = 0.f;
        #pragma unroll 8
        for (int j = 0; j < 32; ++j) {
            int d  = (qd << 5) + j;
            int ed = (e << 7) + d;
            acc = fmaf(w2[ed * 4 + r] * gam[ed], sWqK[d], acc);
        }
        acc += __shfl_xor(acc, 1);
        acc += __shfl_xor(acc, 2);
        if (qd == 0) ws[WS_PKT + (e2 << 6) + (r << 4) + e] = acc;
    }

    if (tid < 192) {
        int kind = tid >> 6;
        int e    = (tid >> 2) & 15;
        int qd   = tid & 3;
        float acc = 0.f;
        #pragma unroll 8
        for (int j = 0; j < 32; ++j) {
            int d  = (qd << 5) + j;
            int ed = (e << 7) + d;
            float w = sWqK[d];
            float t = (kind == 0) ? b2[ed] * gam[ed]
                    : (kind == 1) ? gam[ed]
                                  : bta[ed];
            acc = fmaf(t, w, acc);
        }
        acc += __shfl_xor(acc, 1);
        acc += __shfl_xor(acc, 2);
        if (qd == 0) ws[WS_D1K + (kind << 8) + (e2 << 4) + e] = acc;
    }
}

// ---------------------------------------------------------------------------
// Main kernel v8b: 4096 blocks x 64 thr (1 wave, 4 tokens each).
// Identical to v8 (round-3 infra failure, not a kernel fault) except the
// epilogue LDS transpose is now fenced with __syncthreads() — free for a
// 1-wave block, and removes reliance on intra-wave DS ordering semantics.
//   - Barrier-free K-loop: no LDS staging, no global_load_lds.
//   - Weight rows loaded reg-direct from L1/L2 (160 KB tile shared by all
//     blocks), split 10+10 per chunk with sched_barrier(0) so live w-regs
//     stay at 40 -> ~150 VGPR -> 3 waves/SIMD.
//   - 64-thr workgroups: 12 independent schedulable waves/CU, continuous
//     drain (no block-lockstep rounds, no tail cliff).
//   - h double-buffered in regs; loads issued right after the chunk that
//     frees the buffer (~880 cy cover x 3 waves/SIMD > 900 cy HBM latency).
// ---------------------------------------------------------------------------
__global__ __launch_bounds__(64) void hr_main(
    const float* __restrict__ hidden, const float* __restrict__ wv,
    const float* __restrict__ wvb, const float* __restrict__ w1,
    const float* __restrict__ b1, const float* __restrict__ tab,
    float* __restrict__ out)
{
    __shared__ float lds[1360];    // scat[4][20][16] + red[4][20]

    const int lane = threadIdx.x;              // 0..63
    const int tok0 = blockIdx.x << 2;
    const int l4   = lane << 2;
    const float* hb  = hidden + (size_t)tok0 * INDIM + l4;
    const float* wvl = wv + l4;
    const float* w1l = w1 + l4;

    float acc[NROWS][4];
    #pragma unroll
    for (int w = 0; w < NROWS; ++w) {
        acc[w][0] = 0.f; acc[w][1] = 0.f; acc[w][2] = 0.f; acc[w][3] = 0.f;
    }

    float4 hA[4], hB[4];
    load_h(hA, hb, 0);
    load_h(hB, hb, CHUNK);

    #pragma unroll 1
    for (int cc = 0; cc < 4; ++cc) {
        const int g0 = cc << 9;                 // chunk 2cc
        chunk(acc, wvl, w1l, g0, hA);
        if (cc < 3) load_h(hA, hb, g0 + 512);   // chunk 2cc+2
        chunk(acc, wvl, w1l, g0 + 256, hB);
        if (cc < 3) load_h(hB, hb, g0 + 768);   // chunk 2cc+3
    }

    // ---- wave-local reduction: 2 butterfly levels -> 16 partials ----
    #pragma unroll
    for (int w = 0; w < NROWS; ++w) {
        #pragma unroll
        for (int t = 0; t < 4; ++t) {
            float v = acc[w][t];
            v += __shfl_xor(v, 32);
            v += __shfl_xor(v, 16);
            acc[w][t] = v;     // lane l holds partial for i = l&15
        }
    }
    // scatter: quarter q = lane>>4 writes rows 5q..5q+4 (2 lanes/bank = free)
    {
        const int q = lane >> 4, i = lane & 15;
        #pragma unroll
        for (int w = 0; w < NROWS; ++w) {
            if (q == w / 5) {
                #pragma unroll
                for (int t = 0; t < 4; ++t)
                    lds[t * LSCAT_T + (w << 4) + i] = acc[w][t];
            }
        }
    }
    __syncthreads();   // 1-wave block: effectively free, guarantees ordering

    // gather: 80 (t,w) pairs, sum 16 partials each -> red[t][w]
    #pragma unroll
    for (int pp = 0; pp < 2; ++pp) {
        const int p = lane + (pp << 6);
        if (p < 80) {
            const int t = p / 20, w = p % 20;
            const float4* rp = (const float4*)&lds[t * LSCAT_T + (w << 4)];
            float4 r0 = rp[0], r1 = rp[1], r2 = rp[2], r3 = rp[3];
            float s = (r0.x + r0.y + r0.z + r0.w) + (r1.x + r1.y + r1.z + r1.w)
                    + (r2.x + r2.y + r2.z + r2.w) + (r3.x + r3.y + r3.z + r3.w);
            lds[LRED + t * 20 + w] = s;
        }
    }
    __syncthreads();   // 1-wave block: effectively free

    // ---- tail: 16 threads per token, thread = (tok, e) ----
    const int tok = lane >> 4;
    const int e   = lane & 15;

    float ig[16];
    #pragma unroll
    for (int j = 0; j < 16; ++j) ig[j] = lds[LRED + tok * 20 + j] + wvb[j];
    float h2[4];
    #pragma unroll
    for (int r = 0; r < 4; ++r) h2[r] = fmaxf(lds[LRED + tok * 20 + 16 + r] + b1[r], 0.f);

    float muT = tab[WS_SCAL + 0];
    float e2m = tab[WS_SCAL + 1];
    #pragma unroll
    for (int r = 0; r < 4; ++r) {
        muT = fmaf(h2[r], tab[WS_SCAL + 2 + r], muT);
        e2m = fmaf(2.f * h2[r], tab[WS_SCAL + 6 + r], e2m);
        #pragma unroll
        for (int r2 = 0; r2 < 4; ++r2)
            e2m = fmaf(h2[r] * h2[r2], tab[WS_SCAL + 10 + r * 4 + r2], e2m);
    }
    const float var = e2m - muT * muT;
    const float rsq = rsqrtf(var + 1e-5f);

    float sv[16];
    #pragma unroll
    for (int e2 = 0; e2 < 16; ++e2) {
        float s = tab[WS_D1K + (e2 << 4) + e];
        s = fmaf(h2[0], tab[(e2 << 6) + e], s);
        s = fmaf(h2[1], tab[(e2 << 6) + 16 + e], s);
        s = fmaf(h2[2], tab[(e2 << 6) + 32 + e], s);
        s = fmaf(h2[3], tab[(e2 << 6) + 48 + e], s);
        s = fmaf(-muT, tab[WS_GQK + (e2 << 4) + e], s);
        sv[e2] = (rsq * s + tab[WS_BQK + (e2 << 4) + e]) * SIM_SCALE;
    }
    float mx = sv[0];
    #pragma unroll
    for (int e2 = 1; e2 < 16; ++e2) mx = fmaxf(mx, sv[e2]);
    float den = 0.f, gate = 0.f;
    #pragma unroll
    for (int e2 = 0; e2 < 16; ++e2) {
        float p = __expf(sv[e2] - mx);
        den += p;
        gate = fmaf(p, ig[e2], gate);
    }
    gate /= den;

    float gm = gate;
    gm = fmaxf(gm, __shfl_xor(gm, 1));
    gm = fmaxf(gm, __shfl_xor(gm, 2));
    gm = fmaxf(gm, __shfl_xor(gm, 4));
    gm = fmaxf(gm, __shfl_xor(gm, 8));
    float ex = __expf(gate - gm);
    float es = ex;
    es += __shfl_xor(es, 1);
    es += __shfl_xor(es, 2);
    es += __shfl_xor(es, 4);
    es += __shfl_xor(es, 8);
    const float rw = ex / es;

    float v1 = rw; int i1 = e;
    #pragma unroll
    for (int m = 1; m <= 8; m <<= 1) {
        float ov = __shfl_xor(v1, m);
        int   oi = __shfl_xor(i1, m);
        if (ov > v1 || (ov == v1 && oi < i1)) { v1 = ov; i1 = oi; }
    }
    float v2 = (e == i1) ? -INFINITY : rw; int i2 = e;
    #pragma unroll
    for (int m = 1; m <= 8; m <<= 1) {
        float ov = __shfl_xor(v2, m);
        int   oi = __shfl_xor(i2, m);
        if (ov > v2 || (ov == v2 && oi < i2)) { v2 = ov; i2 = oi; }
    }

    float oval = 0.f;
    if (e == i1 || e == i2) {
        float t = __expf((v2 - v1) * 10.f);
        oval = (e == i1) ? (1.f / (1.f + t)) : (t / (1.f + t));
    }
    out[(((size_t)blockIdx.x << 2) + tok) * 16 + e] = oval;
}

// ---------------------------------------------------------------------------
extern "C" void kernel_launch(void* const* d_in, const int* in_sizes, int n_in,
                              void* d_out, int out_size, void* d_ws, size_t ws_size,
                              hipStream_t stream)
{
    const float* hidden = (const float*)d_in[0];   // (4,4096,2048)
    const float* ee     = (const float*)d_in[1];   // (16,128)
    const float* gam    = (const float*)d_in[2];   // (16,128)
    const float* bta    = (const float*)d_in[3];   // (16,128)
    const float* wv     = (const float*)d_in[4];   // (16,2048)
    const float* wvb    = (const float*)d_in[5];   // (16,)
    const float* w1     = (const float*)d_in[6];   // (4,2048)
    const float* b1     = (const float*)d_in[7];   // (4,)
    const float* w2     = (const float*)d_in[8];   // (2048,4)
    const float* b2     = (const float*)d_in[9];   // (2048,)
    const float* wq     = (const float*)d_in[10];  // (128,128)
    const float* wk     = (const float*)d_in[11];  // (128,128)
    float* out = (float*)d_out;
    float* ws  = (float*)d_ws;

    hipLaunchKernelGGL(hr_pre2, dim3(17), dim3(256), 0, stream,
                       ee, gam, bta, w2, b2, wq, wk, ws);
    hipLaunchKernelGGL(hr_main, dim3(NTOK / 4), dim3(64), 0, stream,
                       hidden, wv, wvb, w1, b1, ws, out);
}